// Round 5
// baseline (232.047 us; speedup 1.0000x reference)
//
#include <hip/hip_runtime.h>
#include <hip/hip_bf16.h>
#include <cstdint>
#include <cstddef>

#define S_LEN 2048
#define N_HEADS 16
#define HD 64
#define EMB 1024
#define N_BATCH 2
#define N_BH (N_BATCH * N_HEADS)

typedef __attribute__((ext_vector_type(4))) float f32x4;
typedef __attribute__((ext_vector_type(8))) short short8;      // 16B raw container
typedef __attribute__((ext_vector_type(8))) _Float16 half8;    // f16 MFMA frag

__device__ __forceinline__ f32x4 mfma16h(half8 a, half8 b, f32x4 c) {
    return __builtin_amdgcn_mfma_f32_16x16x32_f16(a, b, c, 0, 0, 0);
}

__device__ __forceinline__ unsigned pkh(float a, float b) {
    return __builtin_bit_cast(unsigned, __builtin_amdgcn_cvt_pkrtz(a, b));
}

#if __has_builtin(__builtin_amdgcn_exp2f)
__device__ __forceinline__ float fast_exp2(float x) { return __builtin_amdgcn_exp2f(x); }
#else
__device__ __forceinline__ float fast_exp2(float x) { return exp2f(x); }
#endif

// ---------------------------------------------------------------------------
// Kernel 1 (prep): blocks [0,3072) QKV projection; [3072,5120) mask pack
// (each block 4 waves x 1024 elems); [5120,5632) Wo fp32->f16.
// ---------------------------------------------------------------------------
__global__ __launch_bounds__(256) void prep_kernel(
    const float* __restrict__ q_in, const float* __restrict__ k_in,
    const float* __restrict__ v_in,
    const float* __restrict__ Wq, const float* __restrict__ Wk,
    const float* __restrict__ Wv, const float* __restrict__ Wo,
    const int* __restrict__ mask,
    short* __restrict__ Qb, short* __restrict__ Kb, short* __restrict__ Vt,
    short* __restrict__ Woh, unsigned long long* __restrict__ bits) {
    __shared__ short Al[64 * 72];
    __shared__ short Wl[64 * 72];
    __shared__ short Ol[64 * 72];
    int bx = blockIdx.x;
    int t = threadIdx.x;

    if (bx >= 3072) {
        if (bx < 5120) {
            // ---- mask pack: each wave handles 1024 elems = 16 ballots ----
            int gw = (bx - 3072) * 4 + (t >> 6);
            int lane = t & 63;
            const int* src = mask + (size_t)gw * 1024 + lane;
            unsigned long long* dst = bits + (size_t)gw * 16;
#pragma unroll
            for (int r = 0; r < 16; r++) {
                unsigned long long w = __ballot(src[r * 64] != 0);
                if (lane == 0) dst[r] = w;
            }
        } else {
            // ---- Wo fp32 -> f16 (8 floats/thread) ----
            int i = (bx - 5120) * 256 + t;
            f32x4 a = reinterpret_cast<const f32x4*>(Wo)[i * 2];
            f32x4 b = reinterpret_cast<const f32x4*>(Wo)[i * 2 + 1];
            uint4 u = { pkh(a.x, a.y), pkh(a.z, a.w), pkh(b.x, b.y), pkh(b.z, b.w) };
            reinterpret_cast<uint4*>(Woh)[i] = u;
        }
        return;
    }

    // ---- QKV projection ----
    int rt = bx & 31;           // row tile
    int bh = (bx >> 5) & 31;    // head
    int tz = bx >> 10;          // 0:Q 1:K 2:V
    const float* src = (tz == 0 ? q_in : tz == 1 ? k_in : v_in)
                       + (size_t)bh * S_LEN * HD + (size_t)rt * 64 * HD;
    const float* W = (tz == 0 ? Wq : tz == 1 ? Wk : Wv);

#pragma unroll
    for (int r = 0; r < 4; r++) {
        int f4 = t + 256 * r;
        int row = f4 >> 4;
        int c4 = (f4 & 15) * 4;
        f32x4 a = reinterpret_cast<const f32x4*>(src)[f4];
        uint2 ua = { pkh(a.x, a.y), pkh(a.z, a.w) };
        *reinterpret_cast<uint2*>(&Al[row * 72 + c4]) = ua;
        f32x4 w = reinterpret_cast<const f32x4*>(W)[f4];
        uint2 uw = { pkh(w.x, w.y), pkh(w.z, w.w) };
        *reinterpret_cast<uint2*>(&Wl[row * 72 + c4]) = uw;
    }
    __syncthreads();

    int wave = t >> 6, lane = t & 63, quad = lane >> 4, col = lane & 15;
    half8 a0 = *reinterpret_cast<const half8*>(&Al[(wave * 16 + col) * 72 + quad * 8]);
    half8 a1 = *reinterpret_cast<const half8*>(&Al[(wave * 16 + col) * 72 + 32 + quad * 8]);

    const float C1 = 0.04508422002777448f;  // log2(e)/32
    float scl = (tz == 0) ? C1 : 1.0f;

    f32x4 acc[4];
#pragma unroll
    for (int jt = 0; jt < 4; jt++) {
        half8 b0 = *reinterpret_cast<const half8*>(&Wl[(jt * 16 + col) * 72 + quad * 8]);
        half8 b1 = *reinterpret_cast<const half8*>(&Wl[(jt * 16 + col) * 72 + 32 + quad * 8]);
        f32x4 c = {0.f, 0.f, 0.f, 0.f};
        c = mfma16h(a0, b0, c);
        c = mfma16h(a1, b1, c);
        acc[jt] = c;
    }
    __syncthreads();

    if (tz < 2) {
#pragma unroll
        for (int jt = 0; jt < 4; jt++)
#pragma unroll
            for (int i = 0; i < 4; i++)
                Ol[(wave * 16 + quad * 4 + i) * 72 + jt * 16 + col] =
                    __builtin_bit_cast(short, (_Float16)(acc[jt][i] * scl));
        __syncthreads();
        short* dst = (tz == 0 ? Qb : Kb) + (size_t)bh * S_LEN * HD + (size_t)rt * 64 * HD;
        int row = t >> 2, ck = (t & 3) * 16;
        short8 o0 = *reinterpret_cast<const short8*>(&Ol[row * 72 + ck]);
        short8 o1 = *reinterpret_cast<const short8*>(&Ol[row * 72 + ck + 8]);
        *reinterpret_cast<short8*>(&dst[row * 64 + ck]) = o0;
        *reinterpret_cast<short8*>(&dst[row * 64 + ck + 8]) = o1;
    } else {
#pragma unroll
        for (int jt = 0; jt < 4; jt++)
#pragma unroll
            for (int i = 0; i < 4; i++)
                Ol[(jt * 16 + col) * 72 + wave * 16 + quad * 4 + i] =
                    __builtin_bit_cast(short, (_Float16)acc[jt][i]);
        __syncthreads();
        short* dst = Vt + (size_t)bh * HD * S_LEN + rt * 64;
        int d = t >> 2, ck = (t & 3) * 16;
        short8 o0 = *reinterpret_cast<const short8*>(&Ol[d * 72 + ck]);
        short8 o1 = *reinterpret_cast<const short8*>(&Ol[d * 72 + ck + 8]);
        *reinterpret_cast<short8*>(&dst[(size_t)d * S_LEN + ck]) = o0;
        *reinterpret_cast<short8*>(&dst[(size_t)d * S_LEN + ck + 8]) = o1;
    }
}

// ---------------------------------------------------------------------------
// Kernel 2: flash attention. 256 threads = 4 waves; each wave owns 32 q
// (2 q-fragments) so every K/V LDS fragment read feeds 2x the MFMAs.
// Softmax denominator accumulated lane-locally in fp32 (no ones-MFMA);
// single cross-quad shuffle reduction at the end.
// ---------------------------------------------------------------------------
__global__ __launch_bounds__(256, 4) void attn_kernel(
    const short* __restrict__ Qb, const short* __restrict__ Kb,
    const short* __restrict__ Vt, const unsigned long long* __restrict__ mbits,
    short* __restrict__ Xb) {
    int qt = blockIdx.x;  // 0..15
    int bh = blockIdx.y;  // 0..31
    int b = bh >> 4;
    int t = threadIdx.x, wave = t >> 6, lane = t & 63, quad = lane >> 4, col = lane & 15;

    __shared__ short Ks[64 * 64];     // [kv][d], 16B chunk c at c^(kv&7)
    __shared__ short Vs[64 * 64];     // [d][kv], 16B chunk c at c^(d&7)
    __shared__ short Pl[8][16 * 72];  // per (wave,u) P[q][kv], stride 72
    short* PwA = &Pl[wave * 2][0];
    short* PwB = &Pl[wave * 2 + 1][0];

    const short* Qh = Qb + (size_t)bh * S_LEN * HD;
    const short* Kh = Kb + (size_t)bh * S_LEN * HD;
    const short* Vh = Vt + (size_t)bh * HD * S_LEN;
    int qb0 = qt * 128 + wave * 32;
    int qA = qb0 + col, qB = qb0 + 16 + col;

    half8 qA0 = *reinterpret_cast<const half8*>(&Qh[(size_t)qA * HD + quad * 8]);
    half8 qA1 = *reinterpret_cast<const half8*>(&Qh[(size_t)qA * HD + 32 + quad * 8]);
    half8 qB0 = *reinterpret_cast<const half8*>(&Qh[(size_t)qB * HD + quad * 8]);
    half8 qB1 = *reinterpret_cast<const half8*>(&Qh[(size_t)qB * HD + 32 + quad * 8]);
    const unsigned long long* mrowA = mbits + (size_t)(b * S_LEN + qA) * 32;
    const unsigned long long* mrowB = mbits + (size_t)(b * S_LEN + qB) * 32;

    // ---- staging: 1024 chunks (16B) of K+V per tile, 4 per thread ----
    int r0 = t >> 3, r1 = r0 + 32, cc = t & 7;
    int dst0 = r0 * 64 + ((cc ^ (r0 & 7)) * 8);
    int dst1 = r1 * 64 + ((cc ^ (r1 & 7)) * 8);
    const short* kg0 = Kh + r0 * HD + cc * 8;             // +4096 per tile
    const short* kg1 = Kh + r1 * HD + cc * 8;
    const short* vg0 = Vh + (size_t)r0 * S_LEN + cc * 8;  // +64 per tile
    const short* vg1 = Vh + (size_t)r1 * S_LEN + cc * 8;

    short8 pk0 = *reinterpret_cast<const short8*>(kg0);
    short8 pk1 = *reinterpret_cast<const short8*>(kg1);
    short8 pv0 = *reinterpret_cast<const short8*>(vg0);
    short8 pv1 = *reinterpret_cast<const short8*>(vg1);
    *reinterpret_cast<short8*>(&Ks[dst0]) = pk0;
    *reinterpret_cast<short8*>(&Ks[dst1]) = pk1;
    *reinterpret_cast<short8*>(&Vs[dst0]) = pv0;
    *reinterpret_cast<short8*>(&Vs[dst1]) = pv1;
    __syncthreads();

    unsigned bs[4];
#pragma unroll
    for (int i = 0; i < 4; i++) bs[i] = 1u << (quad * 4 + i);
    int sw = quad ^ (col & 7);
    unsigned long long mwA = mrowA[0], mwB = mrowB[0];

    f32x4 o[2][4];
    float lA = 0.f, lB = 0.f;
#pragma unroll
    for (int u = 0; u < 2; u++)
#pragma unroll
        for (int dt = 0; dt < 4; dt++) o[u][dt] = (f32x4){0.f, 0.f, 0.f, 0.f};

    for (int kt = 0; kt < 32; kt++) {
        unsigned long long mwA_n, mwB_n;
        if (kt < 31) {
            pk0 = *reinterpret_cast<const short8*>(kg0 + (kt + 1) * 4096);
            pk1 = *reinterpret_cast<const short8*>(kg1 + (kt + 1) * 4096);
            pv0 = *reinterpret_cast<const short8*>(vg0 + (kt + 1) * 64);
            pv1 = *reinterpret_cast<const short8*>(vg1 + (kt + 1) * 64);
            mwA_n = mrowA[kt + 1];
            mwB_n = mrowB[kt + 1];
        }
        // ---- S^T = K·Q^T for both q-frags (K-frags read once) ----
        f32x4 sA[4], sB[4];
#pragma unroll
        for (int mt = 0; mt < 4; mt++) {
            const short* kbase = &Ks[(mt * 16 + col) * 64];
            half8 ka0 = *reinterpret_cast<const half8*>(&kbase[sw * 8]);
            half8 ka1 = *reinterpret_cast<const half8*>(&kbase[(sw ^ 4) * 8]);
            f32x4 cA = {0.f, 0.f, 0.f, 0.f};
            cA = mfma16h(ka0, qA0, cA);
            cA = mfma16h(ka1, qA1, cA);
            sA[mt] = cA;
            f32x4 cB = {0.f, 0.f, 0.f, 0.f};
            cB = mfma16h(ka0, qB0, cB);
            cB = mfma16h(ka1, qB1, cB);
            sB[mt] = cB;
        }
        // ---- lane-local softmax numerators + P to wave-private LDS ----
#pragma unroll
        for (int mt = 0; mt < 4; mt++) {
            unsigned gA = (unsigned)(mwA >> (mt * 16));
            float a0 = fast_exp2((gA & bs[0]) ? sA[mt][0] : -200.0f);
            float a1 = fast_exp2((gA & bs[1]) ? sA[mt][1] : -200.0f);
            float a2 = fast_exp2((gA & bs[2]) ? sA[mt][2] : -200.0f);
            float a3 = fast_exp2((gA & bs[3]) ? sA[mt][3] : -200.0f);
            lA += (a0 + a1) + (a2 + a3);
            uint2 dwA = { pkh(a0, a1), pkh(a2, a3) };
            *reinterpret_cast<uint2*>(&PwA[col * 72 + mt * 16 + quad * 4]) = dwA;
            unsigned gB = (unsigned)(mwB >> (mt * 16));
            float b0 = fast_exp2((gB & bs[0]) ? sB[mt][0] : -200.0f);
            float b1 = fast_exp2((gB & bs[1]) ? sB[mt][1] : -200.0f);
            float b2 = fast_exp2((gB & bs[2]) ? sB[mt][2] : -200.0f);
            float b3 = fast_exp2((gB & bs[3]) ? sB[mt][3] : -200.0f);
            lB += (b0 + b1) + (b2 + b3);
            uint2 dwB = { pkh(b0, b1), pkh(b2, b3) };
            *reinterpret_cast<uint2*>(&PwB[col * 72 + mt * 16 + quad * 4]) = dwB;
        }
        // ---- O^T += V^T · P^T  (V-frags read once, used by both u) ----
#pragma unroll
        for (int c = 0; c < 2; c++) {
            half8 pbA = *reinterpret_cast<const half8*>(&PwA[col * 72 + c * 32 + quad * 8]);
            half8 pbB = *reinterpret_cast<const half8*>(&PwB[col * 72 + c * 32 + quad * 8]);
#pragma unroll
            for (int dt = 0; dt < 4; dt++) {
                half8 va = *reinterpret_cast<const half8*>(
                    &Vs[(dt * 16 + col) * 64 + (((c * 4 + quad) ^ (col & 7)) * 8)]);
                o[0][dt] = mfma16h(va, pbA, o[0][dt]);
                o[1][dt] = mfma16h(va, pbB, o[1][dt]);
            }
        }
        __syncthreads();
        if (kt < 31) {
            *reinterpret_cast<short8*>(&Ks[dst0]) = pk0;
            *reinterpret_cast<short8*>(&Ks[dst1]) = pk1;
            *reinterpret_cast<short8*>(&Vs[dst0]) = pv0;
            *reinterpret_cast<short8*>(&Vs[dst1]) = pv1;
            mwA = mwA_n;
            mwB = mwB_n;
            __syncthreads();
        }
    }

    // ---- denominators: reduce across quads (lanes col, col+16, +32, +48) ----
    lA += __shfl_xor(lA, 16); lA += __shfl_xor(lA, 32);
    lB += __shfl_xor(lB, 16); lB += __shfl_xor(lB, 32);
    float invA = 1.0f / lA, invB = 1.0f / lB;

    // ---- epilogue: normalize, repack via wave-private LDS, store ----
#pragma unroll
    for (int dt = 0; dt < 4; dt++) {
        uint2 dwA = { pkh(o[0][dt][0] * invA, o[0][dt][1] * invA),
                      pkh(o[0][dt][2] * invA, o[0][dt][3] * invA) };
        *reinterpret_cast<uint2*>(&PwA[col * 72 + dt * 16 + quad * 4]) = dwA;
        uint2 dwB = { pkh(o[1][dt][0] * invB, o[1][dt][1] * invB),
                      pkh(o[1][dt][2] * invB, o[1][dt][3] * invB) };
        *reinterpret_cast<uint2*>(&PwB[col * 72 + dt * 16 + quad * 4]) = dwB;
    }
    int rr = lane >> 2, ck = (lane & 3) * 16;
    short8 x0 = *reinterpret_cast<const short8*>(&PwA[rr * 72 + ck]);
    short8 x1 = *reinterpret_cast<const short8*>(&PwA[rr * 72 + ck + 8]);
    short* XrowA = Xb + (size_t)bh * S_LEN * HD + (size_t)(qb0 + rr) * HD;
    *reinterpret_cast<short8*>(&XrowA[ck]) = x0;
    *reinterpret_cast<short8*>(&XrowA[ck + 8]) = x1;
    short8 y0 = *reinterpret_cast<const short8*>(&PwB[rr * 72 + ck]);
    short8 y1 = *reinterpret_cast<const short8*>(&PwB[rr * 72 + ck + 8]);
    short* XrowB = Xb + (size_t)bh * S_LEN * HD + (size_t)(qb0 + 16 + rr) * HD;
    *reinterpret_cast<short8*>(&XrowB[ck]) = y0;
    *reinterpret_cast<short8*>(&XrowB[ck + 8]) = y1;
}

// ---------------------------------------------------------------------------
// Kernel 3: out = X @ Wo^T + bo.  128x128 tile, 512 threads (8 waves), BK=64.
// Wave w: rows m0+(w>>1)*32+{0,16}, cols n0+(w&1)*64 (4 n-frags).
// 16 MFMA per wave-step vs 12 b128 LDS reads. Direct fp32 stores + reg bias.
// ---------------------------------------------------------------------------
__global__ __launch_bounds__(512, 2) void final_kernel(
    const short* __restrict__ Xb, const short* __restrict__ Woh,
    const float* __restrict__ bo, float* __restrict__ out) {
    int nb = blockIdx.x;  // 0..7
    int mb = blockIdx.y;  // 0..31
    int t = threadIdx.x, wave = t >> 6, lane = t & 63, quad = lane >> 4, col = lane & 15;
    int mw2 = wave >> 1, nw = wave & 1;
    __shared__ short Xs[128 * 64];
    __shared__ short Ws[128 * 64];

    int m0 = mb * 128, n0 = nb * 128;
    // staging: 2048 chunks (16B), 4 per thread (2 X + 2 W)
    int r0 = t >> 3, r1 = r0 + 64, cc = t & 7;
    int dst0 = r0 * 64 + ((cc ^ (r0 & 7)) * 8);
    int dst1 = r1 * 64 + ((cc ^ (r1 & 7)) * 8);
    const short* xg0 = Xb + (size_t)(m0 + r0) * EMB + cc * 8;   // +64 per step
    const short* xg1 = Xb + (size_t)(m0 + r1) * EMB + cc * 8;
    const short* wg0 = Woh + (size_t)(n0 + r0) * EMB + cc * 8;
    const short* wg1 = Woh + (size_t)(n0 + r1) * EMB + cc * 8;

    short8 px0 = *reinterpret_cast<const short8*>(xg0);
    short8 px1 = *reinterpret_cast<const short8*>(xg1);
    short8 pw0 = *reinterpret_cast<const short8*>(wg0);
    short8 pw1 = *reinterpret_cast<const short8*>(wg1);
    *reinterpret_cast<short8*>(&Xs[dst0]) = px0;
    *reinterpret_cast<short8*>(&Xs[dst1]) = px1;
    *reinterpret_cast<short8*>(&Ws[dst0]) = pw0;
    *reinterpret_cast<short8*>(&Ws[dst1]) = pw1;
    __syncthreads();

    f32x4 acc[2][4];
#pragma unroll
    for (int mu = 0; mu < 2; mu++)
#pragma unroll
        for (int nf = 0; nf < 4; nf++) acc[mu][nf] = (f32x4){0.f, 0.f, 0.f, 0.f};

    for (int s = 0; s < 16; s++) {
        if (s < 15) {
            px0 = *reinterpret_cast<const short8*>(xg0 + (s + 1) * 64);
            px1 = *reinterpret_cast<const short8*>(xg1 + (s + 1) * 64);
            pw0 = *reinterpret_cast<const short8*>(wg0 + (s + 1) * 64);
            pw1 = *reinterpret_cast<const short8*>(wg1 + (s + 1) * 64);
        }
#pragma unroll
        for (int k2 = 0; k2 < 2; k2++) {
            half8 a[2];
#pragma unroll
            for (int mu = 0; mu < 2; mu++) {
                int rl = mw2 * 32 + mu * 16 + col;
                a[mu] = *reinterpret_cast<const half8*>(
                    &Xs[rl * 64 + (((k2 * 4 + quad) ^ (rl & 7)) * 8)]);
            }
#pragma unroll
            for (int nf = 0; nf < 4; nf++) {
                int rl = nw * 64 + nf * 16 + col;
                half8 bfr = *reinterpret_cast<const half8*>(
                    &Ws[rl * 64 + (((k2 * 4 + quad) ^ (rl & 7)) * 8)]);
                acc[0][nf] = mfma16h(a[0], bfr, acc[0][nf]);
                acc[1][nf] = mfma16h(a[1], bfr, acc[1][nf]);
            }
        }
        __syncthreads();
        if (s < 15) {
            *reinterpret_cast<short8*>(&Xs[dst0]) = px0;
            *reinterpret_cast<short8*>(&Xs[dst1]) = px1;
            *reinterpret_cast<short8*>(&Ws[dst0]) = pw0;
            *reinterpret_cast<short8*>(&Ws[dst1]) = pw1;
            __syncthreads();
        }
    }

    // ---- epilogue: bias in regs, direct fp32 stores ----
#pragma unroll
    for (int nf = 0; nf < 4; nf++) {
        int n = n0 + nw * 64 + nf * 16 + col;
        float bb = bo[n];
#pragma unroll
        for (int mu = 0; mu < 2; mu++) {
            int row = m0 + mw2 * 32 + mu * 16 + quad * 4;
#pragma unroll
            for (int i = 0; i < 4; i++)
                out[(size_t)(row + i) * EMB + n] = acc[mu][nf][i] + bb;
        }
    }
}

// ---------------------------------------------------------------------------
extern "C" void kernel_launch(void* const* d_in, const int* in_sizes, int n_in,
                              void* d_out, int out_size, void* d_ws, size_t ws_size,
                              hipStream_t stream) {
    const float* value = (const float*)d_in[0];
    const float* key_  = (const float*)d_in[1];
    const float* query = (const float*)d_in[2];
    const int*   mask  = (const int*)d_in[3];
    const float* Wq = (const float*)d_in[4];
    const float* Wk = (const float*)d_in[5];
    const float* Wv = (const float*)d_in[6];
    const float* Wo = (const float*)d_in[7];
    const float* bo = (const float*)d_in[8];
    float* out = (float*)d_out;

    char* ws = (char*)d_ws;
    short* Qb  = (short*)(ws);
    short* Kb  = (short*)(ws + (size_t)8  * 1048576);
    short* Vt  = (short*)(ws + (size_t)16 * 1048576);
    short* Xb  = (short*)(ws + (size_t)24 * 1048576);
    short* Woh = (short*)(ws + (size_t)32 * 1048576);
    unsigned long long* mbits =
        (unsigned long long*)(ws + (size_t)34 * 1048576);

    prep_kernel<<<dim3(3072 + 2048 + 512), dim3(256), 0, stream>>>(
        query, key_, value, Wq, Wk, Wv, Wo, mask, Qb, Kb, Vt, Woh, mbits);
    attn_kernel<<<dim3(S_LEN / 128, N_BH), dim3(256), 0, stream>>>(Qb, Kb, Vt, mbits, Xb);
    final_kernel<<<dim3(EMB / 128, (N_BATCH * S_LEN) / 128), dim3(512), 0, stream>>>(
        Xb, Woh, bo, out);
}

// Round 6
// 212.715 us; speedup vs baseline: 1.0909x; 1.0909x over previous
//
#include <hip/hip_runtime.h>
#include <hip/hip_bf16.h>
#include <cstdint>
#include <cstddef>

#define S_LEN 2048
#define N_HEADS 16
#define HD 64
#define EMB 1024
#define N_BATCH 2
#define N_BH (N_BATCH * N_HEADS)

typedef __attribute__((ext_vector_type(4))) float f32x4;
typedef __attribute__((ext_vector_type(16))) float f32x16;
typedef __attribute__((ext_vector_type(8))) short short8;      // 16B raw container
typedef __attribute__((ext_vector_type(8))) _Float16 half8;    // f16 MFMA frag

__device__ __forceinline__ f32x4 mfma16h(half8 a, half8 b, f32x4 c) {
    return __builtin_amdgcn_mfma_f32_16x16x32_f16(a, b, c, 0, 0, 0);
}
__device__ __forceinline__ f32x16 mfma32h(half8 a, half8 b, f32x16 c) {
    return __builtin_amdgcn_mfma_f32_32x32x16_f16(a, b, c, 0, 0, 0);
}

__device__ __forceinline__ unsigned pkh(float a, float b) {
    return __builtin_bit_cast(unsigned, __builtin_amdgcn_cvt_pkrtz(a, b));
}

#if __has_builtin(__builtin_amdgcn_exp2f)
__device__ __forceinline__ float fast_exp2(float x) { return __builtin_amdgcn_exp2f(x); }
#else
__device__ __forceinline__ float fast_exp2(float x) { return exp2f(x); }
#endif

// ---------------------------------------------------------------------------
// Kernel 1 (prep): blocks [0,3072) QKV projection; [3072,5120) mask pack
// (TRANSPOSED: bitsT[(b*32 + word)][q] so attn reads are coalesced);
// [5120,5632) Wo fp32->f16.
// ---------------------------------------------------------------------------
__global__ __launch_bounds__(256) void prep_kernel(
    const float* __restrict__ q_in, const float* __restrict__ k_in,
    const float* __restrict__ v_in,
    const float* __restrict__ Wq, const float* __restrict__ Wk,
    const float* __restrict__ Wv, const float* __restrict__ Wo,
    const int* __restrict__ mask,
    short* __restrict__ Qb, short* __restrict__ Kb, short* __restrict__ Vt,
    short* __restrict__ Woh, unsigned long long* __restrict__ bits) {
    __shared__ short Al[64 * 72];
    __shared__ short Wl[64 * 72];
    __shared__ short Ol[64 * 72];
    int bx = blockIdx.x;
    int t = threadIdx.x;

    if (bx >= 3072) {
        if (bx < 5120) {
            // ---- mask pack, transposed: word w of row q -> bits[(b*32+w)<<11 | q]
            int gw = (bx - 3072) * 4 + (t >> 6);  // wave id over 8192 waves
            int lane = t & 63;
            const int* src = mask + (size_t)gw * 1024 + lane;
            int row = gw >> 1;
            int bb = row >> 11, qq = row & 2047;
            int wbase = (gw & 1) * 16;
#pragma unroll
            for (int r = 0; r < 16; r++) {
                unsigned long long w = __ballot(src[r * 64] != 0);
                if (lane == 0)
                    bits[((size_t)(bb * 32 + wbase + r) << 11) + qq] = w;
            }
        } else {
            // ---- Wo fp32 -> f16 (8 floats/thread) ----
            int i = (bx - 5120) * 256 + t;
            f32x4 a = reinterpret_cast<const f32x4*>(Wo)[i * 2];
            f32x4 b = reinterpret_cast<const f32x4*>(Wo)[i * 2 + 1];
            uint4 u = { pkh(a.x, a.y), pkh(a.z, a.w), pkh(b.x, b.y), pkh(b.z, b.w) };
            reinterpret_cast<uint4*>(Woh)[i] = u;
        }
        return;
    }

    // ---- QKV projection (Q pre-scaled by log2(e)/32) ----
    int rt = bx & 31;
    int bh = (bx >> 5) & 31;
    int tz = bx >> 10;
    const float* src = (tz == 0 ? q_in : tz == 1 ? k_in : v_in)
                       + (size_t)bh * S_LEN * HD + (size_t)rt * 64 * HD;
    const float* W = (tz == 0 ? Wq : tz == 1 ? Wk : Wv);

#pragma unroll
    for (int r = 0; r < 4; r++) {
        int f4 = t + 256 * r;
        int row = f4 >> 4;
        int c4 = (f4 & 15) * 4;
        f32x4 a = reinterpret_cast<const f32x4*>(src)[f4];
        uint2 ua = { pkh(a.x, a.y), pkh(a.z, a.w) };
        *reinterpret_cast<uint2*>(&Al[row * 72 + c4]) = ua;
        f32x4 w = reinterpret_cast<const f32x4*>(W)[f4];
        uint2 uw = { pkh(w.x, w.y), pkh(w.z, w.w) };
        *reinterpret_cast<uint2*>(&Wl[row * 72 + c4]) = uw;
    }
    __syncthreads();

    int wave = t >> 6, lane = t & 63, quad = lane >> 4, col = lane & 15;
    half8 a0 = *reinterpret_cast<const half8*>(&Al[(wave * 16 + col) * 72 + quad * 8]);
    half8 a1 = *reinterpret_cast<const half8*>(&Al[(wave * 16 + col) * 72 + 32 + quad * 8]);

    const float C1 = 0.04508422002777448f;  // log2(e)/32
    float scl = (tz == 0) ? C1 : 1.0f;

    f32x4 acc[4];
#pragma unroll
    for (int jt = 0; jt < 4; jt++) {
        half8 b0 = *reinterpret_cast<const half8*>(&Wl[(jt * 16 + col) * 72 + quad * 8]);
        half8 b1 = *reinterpret_cast<const half8*>(&Wl[(jt * 16 + col) * 72 + 32 + quad * 8]);
        f32x4 c = {0.f, 0.f, 0.f, 0.f};
        c = mfma16h(a0, b0, c);
        c = mfma16h(a1, b1, c);
        acc[jt] = c;
    }
    __syncthreads();

    if (tz < 2) {
#pragma unroll
        for (int jt = 0; jt < 4; jt++)
#pragma unroll
            for (int i = 0; i < 4; i++)
                Ol[(wave * 16 + quad * 4 + i) * 72 + jt * 16 + col] =
                    __builtin_bit_cast(short, (_Float16)(acc[jt][i] * scl));
        __syncthreads();
        short* dst = (tz == 0 ? Qb : Kb) + (size_t)bh * S_LEN * HD + (size_t)rt * 64 * HD;
        int row = t >> 2, ck = (t & 3) * 16;
        short8 o0 = *reinterpret_cast<const short8*>(&Ol[row * 72 + ck]);
        short8 o1 = *reinterpret_cast<const short8*>(&Ol[row * 72 + ck + 8]);
        *reinterpret_cast<short8*>(&dst[row * 64 + ck]) = o0;
        *reinterpret_cast<short8*>(&dst[row * 64 + ck + 8]) = o1;
    } else {
#pragma unroll
        for (int jt = 0; jt < 4; jt++)
#pragma unroll
            for (int i = 0; i < 4; i++)
                Ol[(jt * 16 + col) * 72 + wave * 16 + quad * 4 + i] =
                    __builtin_bit_cast(short, (_Float16)acc[jt][i]);
        __syncthreads();
        short* dst = Vt + (size_t)bh * HD * S_LEN + rt * 64;
        int d = t >> 2, ck = (t & 3) * 16;
        short8 o0 = *reinterpret_cast<const short8*>(&Ol[d * 72 + ck]);
        short8 o1 = *reinterpret_cast<const short8*>(&Ol[d * 72 + ck + 8]);
        *reinterpret_cast<short8*>(&dst[(size_t)d * S_LEN + ck]) = o0;
        *reinterpret_cast<short8*>(&dst[(size_t)d * S_LEN + ck + 8]) = o1;
    }
}

// ---------------------------------------------------------------------------
// Kernel 2: flash attention, 32x32x16 MFMA. 512 threads = 8 waves =
// 4 q-groups (32 q each, BQ=128) x 2 kv-halves (additive split: fixed-max
// softmax => partial O,l over kv ranges just sum; combined in-block at end).
// K/V staged in double-buffered swizzled LDS (1 barrier/tile). P buffer
// stride 40 f16 (16B-aligned rows, bank-optimal). Mask words transposed ->
// coalesced loads.
// 32x32 layouts: A[m=lane&31][k=(lane>>5)*8+j]; B[k=(lane>>5)*8+j][n=lane&31];
// C/D: col=lane&31, row=(reg&3)+8*(reg>>2)+4*(lane>>5).
// ---------------------------------------------------------------------------
__global__ __launch_bounds__(512, 4) void attn_kernel(
    const short* __restrict__ Qb, const short* __restrict__ Kb,
    const short* __restrict__ Vt, const unsigned long long* __restrict__ mbits,
    short* __restrict__ Xb) {
    int qt = blockIdx.x;  // 0..15
    int bh = blockIdx.y;  // 0..31
    int b = bh >> 4;
    int t = threadIdx.x, wave = t >> 6, lane = t & 63;
    int g = wave & 3, h = wave >> 2;
    int l5 = lane >> 5, l31 = lane & 31;

    // LDS: [0,16384): K/V double buffer (buf b: Ks at b*8192, Vs at b*8192+4096)
    // [16384, 26624): P, 8 waves x 32 rows x stride 40 f16
    // [26624, 26880): lbuf (after main loop)
    __shared__ short smem[26880];
    short* Pg = smem + 16384 + wave * 1280;

    const short* Qh = Qb + (size_t)bh * S_LEN * HD;
    const short* Kh = Kb + (size_t)bh * S_LEN * HD;
    const short* Vh = Vt + (size_t)bh * HD * S_LEN;
    int qbase = qt * 128 + g * 32;
    int q = qbase + l31;

    half8 qf[4];
#pragma unroll
    for (int kc = 0; kc < 4; kc++)
        qf[kc] = *reinterpret_cast<const half8*>(&Qh[(size_t)q * HD + kc * 16 + l5 * 8]);

    const unsigned long long* mcol = mbits + ((size_t)(b * 32) << 11);
    unsigned long long mwq = mcol[q];  // word kt=0 for this q

    // staging: 512 chunks (16B) each for K and V; 1 K + 1 V chunk per thread
    int r0 = t >> 3, cc = t & 7;
    int dstoff = r0 * 64 + ((cc ^ (r0 & 7)) * 8);
    const short* kg0 = Kh + r0 * HD + cc * 8;             // +4096 per tile
    const short* vg0 = Vh + (size_t)r0 * S_LEN + cc * 8;  // +64 per tile

    short8 pk = *reinterpret_cast<const short8*>(kg0);
    short8 pv = *reinterpret_cast<const short8*>(vg0);
    *reinterpret_cast<short8*>(&smem[dstoff]) = pk;
    *reinterpret_cast<short8*>(&smem[4096 + dstoff]) = pv;
    __syncthreads();

    f32x16 o0, o1;
#pragma unroll
    for (int r = 0; r < 16; r++) { o0[r] = 0.f; o1[r] = 0.f; }
    float l_acc = 0.f;
    int krow = h * 32 + l31;

    for (int kt = 0; kt < 32; kt++) {
        unsigned long long mwq_n;
        if (kt < 31) {
            pk = *reinterpret_cast<const short8*>(kg0 + (kt + 1) * 4096);
            pv = *reinterpret_cast<const short8*>(vg0 + (kt + 1) * 64);
            mwq_n = mcol[((size_t)(kt + 1) << 11) + q];
        }
        const short* Kbs = smem + (kt & 1) * 8192;
        const short* Vbs = Kbs + 4096;

        // ---- S^T = K·Q^T for this wave's kv-half (4 MFMAs) ----
        f32x16 s;
#pragma unroll
        for (int r = 0; r < 16; r++) s[r] = 0.f;
#pragma unroll
        for (int kc = 0; kc < 4; kc++) {
            half8 ka = *reinterpret_cast<const half8*>(
                &Kbs[krow * 64 + (((kc * 2 + l5) ^ (krow & 7)) * 8)]);
            s = mfma32h(ka, qf[kc], s);
        }
        // ---- lane-local softmax numerator ----
        unsigned gs = (unsigned)(mwq >> (h * 32)) >> (4 * l5);
        float p[16];
#pragma unroll
        for (int r = 0; r < 16; r++) {
            int bitc = (r & 3) + 8 * (r >> 2);
            p[r] = fast_exp2(((gs >> bitc) & 1u) ? s[r] : -200.0f);
            l_acc += p[r];
        }
        // ---- P to wave-private LDS (stride 40) ----
#pragma unroll
        for (int u = 0; u < 4; u++) {
            uint2 dw = { pkh(p[4 * u], p[4 * u + 1]), pkh(p[4 * u + 2], p[4 * u + 3]) };
            *reinterpret_cast<uint2*>(&Pg[l31 * 40 + 4 * l5 + 8 * u]) = dw;
        }
        // ---- O^T += V^T · P^T over kv-half (4 MFMAs) ----
#pragma unroll
        for (int c = 0; c < 2; c++) {
            half8 pb = *reinterpret_cast<const half8*>(&Pg[l31 * 40 + c * 16 + l5 * 8]);
            {
                int vrow = l31;  // dm=0
                half8 va = *reinterpret_cast<const half8*>(
                    &Vbs[vrow * 64 + (((h * 4 + c * 2 + l5) ^ (vrow & 7)) * 8)]);
                o0 = mfma32h(va, pb, o0);
            }
            {
                int vrow = 32 + l31;  // dm=1
                half8 va = *reinterpret_cast<const half8*>(
                    &Vbs[vrow * 64 + (((h * 4 + c * 2 + l5) ^ (vrow & 7)) * 8)]);
                o1 = mfma32h(va, pb, o1);
            }
        }
        // ---- stage next tile into other buffer, single barrier ----
        if (kt < 31) {
            short* nb = smem + ((kt + 1) & 1) * 8192;
            *reinterpret_cast<short8*>(&nb[dstoff]) = pk;
            *reinterpret_cast<short8*>(&nb[4096 + dstoff]) = pv;
            mwq = mwq_n;
        }
        __syncthreads();
    }

    // ---- combine kv-halves (additive) ----
    l_acc += __shfl_xor(l_acc, 32);
    float* obuf = (float*)smem;              // overlays K/V buffers (32 KB)
    float* lbuf = (float*)(smem + 26624);
    if (h == 1) {
#pragma unroll
        for (int r = 0; r < 16; r++) {
            obuf[(g * 32 + r) * 64 + lane] = o0[r];
            obuf[(g * 32 + 16 + r) * 64 + lane] = o1[r];
        }
        if (lane < 32) lbuf[g * 32 + lane] = l_acc;
    }
    __syncthreads();
    if (h == 0) {
        float inv = 1.0f / (l_acc + lbuf[g * 32 + l31]);
#pragma unroll
        for (int r = 0; r < 16; r++) {
            o0[r] = (o0[r] + obuf[(g * 32 + r) * 64 + lane]) * inv;
            o1[r] = (o1[r] + obuf[(g * 32 + 16 + r) * 64 + lane]) * inv;
        }
        short* Xrow = Xb + (size_t)bh * S_LEN * HD + (size_t)q * HD;
#pragma unroll
        for (int u = 0; u < 4; u++) {
            uint2 w0 = { pkh(o0[4 * u], o0[4 * u + 1]), pkh(o0[4 * u + 2], o0[4 * u + 3]) };
            *reinterpret_cast<uint2*>(&Xrow[4 * l5 + 8 * u]) = w0;
            uint2 w1 = { pkh(o1[4 * u], o1[4 * u + 1]), pkh(o1[4 * u + 2], o1[4 * u + 3]) };
            *reinterpret_cast<uint2*>(&Xrow[32 + 4 * l5 + 8 * u]) = w1;
        }
    }
}

// ---------------------------------------------------------------------------
// Kernel 3: out = X @ Wo^T + bo.  128m x 64n tile, 512 thr (8 waves x 16 m),
// BK=64, double-buffered staging, 1 barrier/step. grid 512 = 2 blocks/CU.
// ---------------------------------------------------------------------------
__global__ __launch_bounds__(512, 4) void final_kernel(
    const short* __restrict__ Xb, const short* __restrict__ Woh,
    const float* __restrict__ bo, float* __restrict__ out) {
    int nb = blockIdx.x;  // 0..15
    int mb = blockIdx.y;  // 0..31
    int t = threadIdx.x, wave = t >> 6, lane = t & 63, quad = lane >> 4, col = lane & 15;
    // LDS: Xs buf b at b*8192 (128x64), Ws buf b at 16384 + b*4096 (64x64)
    __shared__ short smem[24576];

    int m0 = mb * 128, n0 = nb * 64;
    int r0 = t >> 3, r1 = r0 + 64, cc = t & 7;
    int dx0 = r0 * 64 + ((cc ^ (r0 & 7)) * 8);
    int dx1 = r1 * 64 + ((cc ^ (r1 & 7)) * 8);
    const short* xg0 = Xb + (size_t)(m0 + r0) * EMB + cc * 8;   // +64 per step
    const short* xg1 = Xb + (size_t)(m0 + r1) * EMB + cc * 8;
    const short* wg0 = Woh + (size_t)(n0 + r0) * EMB + cc * 8;

    short8 px0 = *reinterpret_cast<const short8*>(xg0);
    short8 px1 = *reinterpret_cast<const short8*>(xg1);
    short8 pw0 = *reinterpret_cast<const short8*>(wg0);
    *reinterpret_cast<short8*>(&smem[dx0]) = px0;
    *reinterpret_cast<short8*>(&smem[dx1]) = px1;
    *reinterpret_cast<short8*>(&smem[16384 + dx0]) = pw0;
    __syncthreads();

    f32x4 acc[4];
#pragma unroll
    for (int nf = 0; nf < 4; nf++) acc[nf] = (f32x4){0.f, 0.f, 0.f, 0.f};
    int arow = wave * 16 + col;

    for (int s = 0; s < 16; s++) {
        if (s < 15) {
            px0 = *reinterpret_cast<const short8*>(xg0 + (s + 1) * 64);
            px1 = *reinterpret_cast<const short8*>(xg1 + (s + 1) * 64);
            pw0 = *reinterpret_cast<const short8*>(wg0 + (s + 1) * 64);
        }
        const short* Xs = smem + (s & 1) * 8192;
        const short* Ws = smem + 16384 + (s & 1) * 4096;
#pragma unroll
        for (int k2 = 0; k2 < 2; k2++) {
            half8 a = *reinterpret_cast<const half8*>(
                &Xs[arow * 64 + (((k2 * 4 + quad) ^ (arow & 7)) * 8)]);
#pragma unroll
            for (int nf = 0; nf < 4; nf++) {
                int brow = nf * 16 + col;
                half8 bf = *reinterpret_cast<const half8*>(
                    &Ws[brow * 64 + (((k2 * 4 + quad) ^ (brow & 7)) * 8)]);
                acc[nf] = mfma16h(a, bf, acc[nf]);
            }
        }
        if (s < 15) {
            short* Xn = smem + ((s + 1) & 1) * 8192;
            short* Wn = smem + 16384 + ((s + 1) & 1) * 4096;
            *reinterpret_cast<short8*>(&Xn[dx0]) = px0;
            *reinterpret_cast<short8*>(&Xn[dx1]) = px1;
            *reinterpret_cast<short8*>(&Wn[dx0]) = pw0;
        }
        __syncthreads();
    }

    // ---- epilogue: bias in regs, direct fp32 stores ----
#pragma unroll
    for (int nf = 0; nf < 4; nf++) {
        int n = n0 + nf * 16 + col;
        float bb = bo[n];
        int rowb = m0 + wave * 16 + quad * 4;
#pragma unroll
        for (int i = 0; i < 4; i++)
            out[(size_t)(rowb + i) * EMB + n] = acc[nf][i] + bb;
    }
}

// ---------------------------------------------------------------------------
extern "C" void kernel_launch(void* const* d_in, const int* in_sizes, int n_in,
                              void* d_out, int out_size, void* d_ws, size_t ws_size,
                              hipStream_t stream) {
    const float* value = (const float*)d_in[0];
    const float* key_  = (const float*)d_in[1];
    const float* query = (const float*)d_in[2];
    const int*   mask  = (const int*)d_in[3];
    const float* Wq = (const float*)d_in[4];
    const float* Wk = (const float*)d_in[5];
    const float* Wv = (const float*)d_in[6];
    const float* Wo = (const float*)d_in[7];
    const float* bo = (const float*)d_in[8];
    float* out = (float*)d_out;

    char* ws = (char*)d_ws;
    short* Qb  = (short*)(ws);
    short* Kb  = (short*)(ws + (size_t)8  * 1048576);
    short* Vt  = (short*)(ws + (size_t)16 * 1048576);
    short* Xb  = (short*)(ws + (size_t)24 * 1048576);
    short* Woh = (short*)(ws + (size_t)32 * 1048576);
    unsigned long long* mbits =
        (unsigned long long*)(ws + (size_t)34 * 1048576);

    prep_kernel<<<dim3(3072 + 2048 + 512), dim3(256), 0, stream>>>(
        query, key_, value, Wq, Wk, Wv, Wo, mask, Qb, Kb, Vt, Woh, mbits);
    attn_kernel<<<dim3(S_LEN / 128, N_BH), dim3(512), 0, stream>>>(Qb, Kb, Vt, mbits, Xb);
    final_kernel<<<dim3(EMB / 64, (N_BATCH * S_LEN) / 128), dim3(512), 0, stream>>>(
        Xb, Woh, bo, out);
}